// Round 2
// baseline (159.938 us; speedup 1.0000x reference)
//
#include <hip/hip_runtime.h>

// VisionPooler: 3x3 mean-pool over 48x48 patch grid, x sqrt(768).
// B=16, G=48, D=768, K=3  ->  N=2304 patches, L=256 bins.
// Output: [B*L, D] f32 pooled, then [B*L] valid_mask (all-True -> 1.0f).
//
// Pure streaming kernel: 113.2 MB read once + 12.6 MB written once.
// Rev 2: (a) 2 adjacent bins (same ky) per block -> 18 KB contiguous read
// per grid row, 18 loads in flight per thread, half the block count;
// (b) mask written coalesced by one dedicated block instead of 4096
// scattered single-dword stores.

#define B  16
#define G  48
#define D  768
#define NN (G * G)           // 2304 patches per image
#define LL 256               // output bins per image
#define D4 (D / 4)           // 192 float4 per row
#define OUT_ELEMS (B * LL * D)
#define MAIN_BLOCKS (B * LL / 2)   // 2048: each handles bin pair (2i, 2i+1)

typedef float f32x4 __attribute__((ext_vector_type(4)));

__global__ __launch_bounds__(192) void pool_kernel(const float* __restrict__ h,
                                                   float* __restrict__ out,
                                                   int n_mask) {
    const int blk = blockIdx.x;

    // Last block: coalesced valid_mask write (all-True by construction).
    if (blk == MAIN_BLOCKS) {
        for (int i = threadIdx.x; i < n_mask; i += 192)
            out[(size_t)OUT_ELEMS + i] = 1.0f;
        return;
    }

    const int bl = blk * 2;             // first bin of the pair (even)
    const int b  = bl >> 8;             // image
    const int l  = bl & 255;            // bin (even -> kx even, kx+1 same ky)
    const int kx = l & 15;              // bin column (16 per grid row)
    const int ky = l >> 4;              // bin row
    const int t  = threadIdx.x;         // 0..191

    const f32x4* __restrict__ base =
        reinterpret_cast<const f32x4*>(h) + (size_t)b * NN * D4 + t;

    // Grid-row starts of the 3 patch rows; bins (l, l+1) span 6 consecutive
    // patches per row: A = patches 0..2, B = patches 3..5 (18 KB contiguous).
    const size_t n0 = (size_t)((3 * ky) * G + 3 * kx) * D4;
    const size_t rs = (size_t)G * D4;   // grid-row stride in float4

    const f32x4* p0 = base + n0;
    const f32x4* p1 = p0 + rs;
    const f32x4* p2 = p1 + rs;

    // Issue all 18 non-temporal loads before any arithmetic.
    f32x4 a0 = __builtin_nontemporal_load(p0);
    f32x4 a1 = __builtin_nontemporal_load(p0 + D4);
    f32x4 a2 = __builtin_nontemporal_load(p0 + 2 * D4);
    f32x4 b0 = __builtin_nontemporal_load(p0 + 3 * D4);
    f32x4 b1 = __builtin_nontemporal_load(p0 + 4 * D4);
    f32x4 b2 = __builtin_nontemporal_load(p0 + 5 * D4);
    f32x4 a3 = __builtin_nontemporal_load(p1);
    f32x4 a4 = __builtin_nontemporal_load(p1 + D4);
    f32x4 a5 = __builtin_nontemporal_load(p1 + 2 * D4);
    f32x4 b3 = __builtin_nontemporal_load(p1 + 3 * D4);
    f32x4 b4 = __builtin_nontemporal_load(p1 + 4 * D4);
    f32x4 b5 = __builtin_nontemporal_load(p1 + 5 * D4);
    f32x4 a6 = __builtin_nontemporal_load(p2);
    f32x4 a7 = __builtin_nontemporal_load(p2 + D4);
    f32x4 a8 = __builtin_nontemporal_load(p2 + 2 * D4);
    f32x4 b6 = __builtin_nontemporal_load(p2 + 3 * D4);
    f32x4 b7 = __builtin_nontemporal_load(p2 + 4 * D4);
    f32x4 b8 = __builtin_nontemporal_load(p2 + 5 * D4);

    const float s = 3.0792014356780038f;   // sqrt(768) / 9
    f32x4* __restrict__ op = reinterpret_cast<f32x4*>(out) + (size_t)bl * D4 + t;

    // Bin A: tree-sum, scale, store (bin B's loads still in flight behind it).
    f32x4 accA = ((a0 + a1) + (a2 + a3)) + ((a4 + a5) + (a6 + a7)) + a8;
    __builtin_nontemporal_store(accA * s, op);

    // Bin B.
    f32x4 accB = ((b0 + b1) + (b2 + b3)) + ((b4 + b5) + (b6 + b7)) + b8;
    __builtin_nontemporal_store(accB * s, op + D4);
}

extern "C" void kernel_launch(void* const* d_in, const int* in_sizes, int n_in,
                              void* d_out, int out_size, void* d_ws, size_t ws_size,
                              hipStream_t stream) {
    const float* h = (const float*)d_in[0];
    float* out = (float*)d_out;
    const int n_mask = out_size - OUT_ELEMS;   // expected B*LL = 4096

    pool_kernel<<<MAIN_BLOCKS + 1, 192, 0, stream>>>(h, out, n_mask);
}